// Round 6
// baseline (892.946 us; speedup 1.0000x reference)
//
#include <hip/hip_runtime.h>
#include <hip/hip_bf16.h>

// dims
constexpr int BB = 16, IC = 512, OC = 512, HH = 64, WW = 64, HW = 64 * 64, SD = 512;
constexpr float MOD_SCALE = 0.04419417382415922f;      // 1/sqrt(512)
constexpr float CONV_SCALE = 0.014731391274719739f;    // 1/sqrt(512*9)
constexpr float CONV_SCALE2 = 2.170138888888889e-4f;   // 1/4608

typedef float f32x4 __attribute__((ext_vector_type(4)));
typedef short bf16x8 __attribute__((ext_vector_type(8)));

#define VMWAIT(n) asm volatile("s_waitcnt vmcnt(" #n ")" ::: "memory")

__device__ __forceinline__ unsigned short f2bf(float x) {
  __hip_bfloat16 h = __float2bfloat16(x);
  return *(unsigned short*)&h;
}

// ---------------- kernel 1: s[b][ic] = style @ (mod_weight*ms)^T + mod_bias ----
__global__ void k_style(const float* __restrict__ style, const float* __restrict__ mw,
                        const float* __restrict__ mb, float* __restrict__ s) {
  __shared__ float st[SD];
  const int b = blockIdx.x;
  for (int i = threadIdx.x; i < SD; i += 256) st[i] = style[b * SD + i];
  __syncthreads();
  for (int ic = threadIdx.x; ic < IC; ic += 256) {
    const float4* wr = (const float4*)(mw + (size_t)ic * SD);
    float acc = 0.f;
    for (int d = 0; d < SD / 4; ++d) {
      float4 w4 = wr[d];
      float4 s4 = *(const float4*)&st[d * 4];
      acc += w4.x * s4.x + w4.y * s4.y + w4.z * s4.z + w4.w * s4.w;
    }
    s[b * IC + ic] = acc * MOD_SCALE + mb[ic];
  }
}

// ---------------- kernel 2: pack weights [tap][oc][ic] bf16 + w2sum[oc][ic] ----
__global__ void k_pack(const float* __restrict__ w, unsigned short* __restrict__ wpack,
                       float* __restrict__ w2sum) {
  const int oc = blockIdx.x;
  const int ic0 = threadIdx.x * 2;
  const float* p = w + (size_t)oc * IC * 9 + (size_t)ic0 * 9;
  float v[18];
#pragma unroll
  for (int i = 0; i < 18; ++i) v[i] = p[i];
  float s0 = 0.f, s1 = 0.f;
#pragma unroll
  for (int t = 0; t < 9; ++t) { s0 += v[t] * v[t]; s1 += v[9 + t] * v[9 + t]; }
  *(float2*)&w2sum[oc * IC + ic0] = make_float2(s0, s1);
#pragma unroll
  for (int t = 0; t < 9; ++t) {
    unsigned int pk = (unsigned int)f2bf(v[t]) | ((unsigned int)f2bf(v[9 + t]) << 16);
    *(unsigned int*)&wpack[((size_t)t * OC + oc) * IC + ic0] = pk;
  }
}

// ---------------- kernel 3: fscale[b][oc] = conv_scale * rsqrt(cs2*sum + eps) --
__global__ void k_demod(const float* __restrict__ s, const float* __restrict__ w2sum,
                        float* __restrict__ fscale) {
  __shared__ float s2[IC];
  const int b = blockIdx.x;
  for (int i = threadIdx.x; i < IC; i += 256) { float v = s[b * IC + i]; s2[i] = v * v; }
  __syncthreads();
  for (int oc = threadIdx.x; oc < OC; oc += 256) {
    const float4* wr = (const float4*)(w2sum + (size_t)oc * IC);
    float acc = 0.f;
    for (int i4 = 0; i4 < IC / 4; ++i4) {
      float4 w4 = wr[i4];
      float4 q4 = *(const float4*)&s2[i4 * 4];
      acc += w4.x * q4.x + w4.y * q4.y + w4.z * q4.z + w4.w * q4.w;
    }
    fscale[b * OC + oc] = CONV_SCALE * rsqrtf(CONV_SCALE2 * acc + 1e-8f);
  }
}

// ---------------- kernel 4: the conv (implicit GEMM, bf16 MFMA) ----------------
// grid: 2048 = 16 b * 4 mblk * 32 nblk; block 256 (4 waves, 2x2 over 128x128 tile)
// r3 skeleton + two pipeline changes:
//  (1) B-frag cross-tap prefetch: tap t+1's 4 B ds_reads issue during tap t's
//      MFMA cluster (Bsm is stable within an icb). Post-barrier critical path
//      is only the 4 A-frag reads.
//  (2) A DMA 3-deep: 4 rotating buffers, issueA(p+3), steady vmcnt(4).
// Still: 1 raw barrier/phase, stageB inline at t==0 with publish barrier,
// counted vmcnt only (0 only at the very last phase), T5 setprio.
__global__ __launch_bounds__(256, 3) void k_conv(
    const float* __restrict__ x, const unsigned short* __restrict__ wpack,
    const float* __restrict__ s, const float* __restrict__ fscale,
    float* __restrict__ out) {
  __shared__ __align__(128) unsigned short Asm[4][128 * 32];  // [buf][oc_local][ic] swizzled
  __shared__ __align__(128) unsigned short Bsm[264 * 32];     // [h''*66 + w''][ic] swizzled

  const int bx = blockIdx.x;
  const int b = bx >> 7;
  const int mblk = (bx >> 5) & 3;
  const int nblk = bx & 31;

  const int tid = threadIdx.x;
  const int wave = tid >> 6, lane = tid & 63;
  const int wm = wave >> 1, wn = wave & 1;
  const int lrow = lane & 15, lk = lane >> 4;

  const int h0 = nblk * 2;  // this block's 2 output rows; halo rows h0-1..h0+2
  const float* xb = x + (size_t)b * IC * HW;
  const float* sb = s + b * IC;

  f32x4 acc[4][4];
#pragma unroll
  for (int i = 0; i < 4; ++i)
#pragma unroll
    for (int j = 0; j < 4; ++j) acc[i][j] = f32x4{0.f, 0.f, 0.f, 0.f};

  // zero the w-halo rows (w''==0 and w''==65 for the 4 h rows), once
  {
    int q = tid >> 5;  // 0..7
    int hh = q >> 1, wz = (q & 1) ? 65 : 0;
    Bsm[(hh * 66 + wz) * 32 + (tid & 31)] = 0;
  }

  // stage input tile for one 32-ic block: [4 h rows][64 w][32 ic], scaled by s
  auto stageB = [&](int icb) {
    const int hh = wave;     // 0..3
    const int w = lane;      // 0..63
    const int h_abs = h0 - 1 + hh;
    const bool vh = (h_abs >= 0) && (h_abs < HH);
    const int h_safe = vh ? h_abs : 0;
    const int r = hh * 66 + w + 1;
    const int swz = (r >> 1) & 3;
    const float* src = xb + (size_t)(icb * 32) * HW + h_safe * WW + w;
#pragma unroll
    for (int c = 0; c < 4; ++c) {
      unsigned int pk[4];
#pragma unroll
      for (int jj = 0; jj < 4; ++jj) {
        int ic = c * 8 + jj * 2;
        float m0 = vh ? sb[icb * 32 + ic] : 0.f;
        float m1 = vh ? sb[icb * 32 + ic + 1] : 0.f;
        float v0 = src[(size_t)ic * HW] * m0;
        float v1 = src[(size_t)(ic + 1) * HW] * m1;
        pk[jj] = (unsigned int)f2bf(v0) | ((unsigned int)f2bf(v1) << 16);
      }
      int cd = c ^ swz;
      *(uint4*)&Bsm[r * 32 + cd * 8] = make_uint4(pk[0], pk[1], pk[2], pk[3]);
    }
  };

  // async-stage one 128x32 weight tile (2 global_load_lds per wave per call)
  auto issueA = [&](int tap, int icb, int nb) {
    const unsigned short* base =
        wpack + ((size_t)(tap * OC + mblk * 128)) * IC + icb * 32;
#pragma unroll
    for (int q = 0; q < 2; ++q) {
      int r = wave * 32 + q * 16 + (lane >> 2);
      int cs = (lane & 3) ^ ((r >> 1) & 3);
      const unsigned short* g = base + (size_t)r * IC + cs * 8;
      unsigned short* l = &Asm[nb][(wave * 32 + q * 16) * 32];
      __builtin_amdgcn_global_load_lds(
          (const __attribute__((address_space(1))) void*)g,
          (__attribute__((address_space(3))) void*)l, 16, 0, 0);
    }
  };

  // B-frag read for tap tn into dst[4] (4 ds_read_b128)
  auto loadB = [&](bf16x8* dst, int tn) {
    const int dh = tn / 3 - 1, dw = tn % 3 - 1;
    const int hb = wn + dh + 1;
#pragma unroll
    for (int j = 0; j < 4; ++j) {
      int r = hb * 66 + j * 16 + lrow + dw + 1;
      dst[j] = *(const bf16x8*)&Bsm[r * 32 + ((lk ^ ((r >> 1) & 3)) * 8)];
    }
  };

  stageB(0);
  issueA(0, 0, 0);   // D(0) -> buf0
  issueA(1, 0, 1);   // D(1) -> buf1
  issueA(2, 0, 2);   // D(2) -> buf2
  __syncthreads();   // prologue only: full drain + publish

  bf16x8 bfr[2][4];  // [t&1][j], parity-indexed (static within unrolled t)

  for (int icb = 0; icb < 16; ++icb) {
#pragma unroll
    for (int t = 0; t < 9; ++t) {
      // ---- arrival wait for D(p): groups for taps t+1,t+2 may remain ----
      if (icb == 15 && t == 7)      { VMWAIT(2); }
      else if (icb == 15 && t == 8) { VMWAIT(0); }
      else                          { VMWAIT(4); }
      __builtin_amdgcn_s_barrier();          // the ONE barrier per phase
      __builtin_amdgcn_sched_barrier(0);

      if (t == 0) {
        if (icb > 0) {
          // restage B inside the phase; all Bsm reads completed before the
          // arrival barrier above (no cross-icb B prefetch at t==8).
          stageB(icb);
          asm volatile("s_waitcnt lgkmcnt(0)" ::: "memory");
          __builtin_amdgcn_s_barrier();      // publish new Bsm to the block
          __builtin_amdgcn_sched_barrier(0);
        }
        loadB(bfr[0], 0);                    // tap 0's B-frags (in-phase, t==0 only)
      }

      // ---- issue D(p+3) into buf (icb+t+3)&3; barrier(p) proved that buffer
      //      was consumed at phase p-1 ----
      if (t <= 5)          issueA(t + 3, icb, (icb + t + 3) & 3);
      else if (icb < 15)   issueA(t - 6, icb + 1, (icb + t + 3) & 3);

      // ---- A-frags for tap t (the only post-barrier-critical ds_reads) ----
      bf16x8 af[4];
#pragma unroll
      for (int i = 0; i < 4; ++i) {
        int r = wm * 64 + i * 16 + lrow;
        af[i] = *(const bf16x8*)&Asm[(icb + t) & 3][r * 32 + ((lk ^ ((r >> 1) & 3)) * 8)];
      }

      // ---- MFMA cluster; tap t+1's B-frags issue in its shadow ----
      __builtin_amdgcn_s_setprio(1);
#pragma unroll
      for (int j = 0; j < 4; ++j)
        acc[0][j] = __builtin_amdgcn_mfma_f32_16x16x32_bf16(af[0], bfr[t & 1][j],
                                                            acc[0][j], 0, 0, 0);
      if (t < 8) loadB(bfr[(t + 1) & 1], t + 1);   // prefetch next tap's B
#pragma unroll
      for (int i = 1; i < 4; ++i)
#pragma unroll
        for (int j = 0; j < 4; ++j)
          acc[i][j] = __builtin_amdgcn_mfma_f32_16x16x32_bf16(af[i], bfr[t & 1][j],
                                                              acc[i][j], 0, 0, 0);
      __builtin_amdgcn_s_setprio(0);
      __builtin_amdgcn_sched_barrier(0);
      // no second barrier: next phase's arrival barrier bounds skew to <1 phase
    }
  }

  // epilogue: scale by conv_scale*demod[b][oc], coalesced 64B stores
  const float* fsb = fscale + b * OC;
#pragma unroll
  for (int i = 0; i < 4; ++i) {
#pragma unroll
    for (int rr = 0; rr < 4; ++rr) {
      const int oc = mblk * 128 + wm * 64 + i * 16 + lk * 4 + rr;
      const float sc = fsb[oc];
      float* orow = out + ((size_t)(b * OC + oc)) * HW + nblk * 128 + wn * 64 + lrow;
#pragma unroll
      for (int j = 0; j < 4; ++j) orow[j * 16] = acc[i][j][rr] * sc;
    }
  }
}

// ---------------- launch --------------------------------------------------------
extern "C" void kernel_launch(void* const* d_in, const int* in_sizes, int n_in,
                              void* d_out, int out_size, void* d_ws, size_t ws_size,
                              hipStream_t stream) {
  const float* input = (const float*)d_in[0];       // [16,512,64,64]
  const float* style = (const float*)d_in[1];       // [16,512]
  const float* weight = (const float*)d_in[2];      // [1,512,512,3,3]
  const float* mod_weight = (const float*)d_in[3];  // [512,512]
  const float* mod_bias = (const float*)d_in[4];    // [512]
  float* out = (float*)d_out;

  char* ws = (char*)d_ws;
  constexpr size_t WPACK_B = (size_t)9 * OC * IC * 2;   // 4,718,592
  constexpr size_t W2SUM_B = (size_t)OC * IC * 4;       // 1,048,576
  constexpr size_t S_B = (size_t)BB * IC * 4;           // 32,768
  unsigned short* wpack = (unsigned short*)ws;
  float* w2sum = (float*)(ws + WPACK_B);
  float* s = (float*)(ws + WPACK_B + W2SUM_B);
  float* fscale = (float*)(ws + WPACK_B + W2SUM_B + S_B);

  k_style<<<BB, 256, 0, stream>>>(style, mod_weight, mod_bias, s);
  k_pack<<<OC, 256, 0, stream>>>(weight, wpack, w2sum);
  k_demod<<<BB, 256, 0, stream>>>(s, w2sum, fscale);
  k_conv<<<2048, 256, 0, stream>>>(input, wpack, s, fscale, out);
}

// Round 7
// 460.916 us; speedup vs baseline: 1.9373x; 1.9373x over previous
//
#include <hip/hip_runtime.h>
#include <hip/hip_bf16.h>

// dims
constexpr int BB = 16, IC = 512, OC = 512, HH = 64, WW = 64, HW = 64 * 64, SD = 512;
constexpr float MOD_SCALE = 0.04419417382415922f;      // 1/sqrt(512)
constexpr float CONV_SCALE = 0.014731391274719739f;    // 1/sqrt(512*9)
constexpr float CONV_SCALE2 = 2.170138888888889e-4f;   // 1/4608

typedef float f32x4 __attribute__((ext_vector_type(4)));
typedef short bf16x8 __attribute__((ext_vector_type(8)));

#define VMWAIT(n) asm volatile("s_waitcnt vmcnt(" #n ")" ::: "memory")

__device__ __forceinline__ unsigned short f2bf(float x) {
  __hip_bfloat16 h = __float2bfloat16(x);
  return *(unsigned short*)&h;
}

// ---------------- kernel 1: s[b][ic] = style @ (mod_weight*ms)^T + mod_bias ----
__global__ void k_style(const float* __restrict__ style, const float* __restrict__ mw,
                        const float* __restrict__ mb, float* __restrict__ s) {
  __shared__ float st[SD];
  const int b = blockIdx.x;
  for (int i = threadIdx.x; i < SD; i += 256) st[i] = style[b * SD + i];
  __syncthreads();
  for (int ic = threadIdx.x; ic < IC; ic += 256) {
    const float4* wr = (const float4*)(mw + (size_t)ic * SD);
    float acc = 0.f;
    for (int d = 0; d < SD / 4; ++d) {
      float4 w4 = wr[d];
      float4 s4 = *(const float4*)&st[d * 4];
      acc += w4.x * s4.x + w4.y * s4.y + w4.z * s4.z + w4.w * s4.w;
    }
    s[b * IC + ic] = acc * MOD_SCALE + mb[ic];
  }
}

// ---------------- kernel 2: pack weights [tap][oc][ic] bf16 + w2sum[oc][ic] ----
__global__ void k_pack(const float* __restrict__ w, unsigned short* __restrict__ wpack,
                       float* __restrict__ w2sum) {
  const int oc = blockIdx.x;
  const int ic0 = threadIdx.x * 2;
  const float* p = w + (size_t)oc * IC * 9 + (size_t)ic0 * 9;
  float v[18];
#pragma unroll
  for (int i = 0; i < 18; ++i) v[i] = p[i];
  float s0 = 0.f, s1 = 0.f;
#pragma unroll
  for (int t = 0; t < 9; ++t) { s0 += v[t] * v[t]; s1 += v[9 + t] * v[9 + t]; }
  *(float2*)&w2sum[oc * IC + ic0] = make_float2(s0, s1);
#pragma unroll
  for (int t = 0; t < 9; ++t) {
    unsigned int pk = (unsigned int)f2bf(v[t]) | ((unsigned int)f2bf(v[9 + t]) << 16);
    *(unsigned int*)&wpack[((size_t)t * OC + oc) * IC + ic0] = pk;
  }
}

// ---------------- kernel 3: fscale[b][oc] = conv_scale * rsqrt(cs2*sum + eps) --
__global__ void k_demod(const float* __restrict__ s, const float* __restrict__ w2sum,
                        float* __restrict__ fscale) {
  __shared__ float s2[IC];
  const int b = blockIdx.x;
  for (int i = threadIdx.x; i < IC; i += 256) { float v = s[b * IC + i]; s2[i] = v * v; }
  __syncthreads();
  for (int oc = threadIdx.x; oc < OC; oc += 256) {
    const float4* wr = (const float4*)(w2sum + (size_t)oc * IC);
    float acc = 0.f;
    for (int i4 = 0; i4 < IC / 4; ++i4) {
      float4 w4 = wr[i4];
      float4 q4 = *(const float4*)&s2[i4 * 4];
      acc += w4.x * q4.x + w4.y * q4.y + w4.z * q4.z + w4.w * q4.w;
    }
    fscale[b * OC + oc] = CONV_SCALE * rsqrtf(CONV_SCALE2 * acc + 1e-8f);
  }
}

// B-frag read for tap TN into named local array DST[4] (static indices only —
// rule #20: no pointer-passing, must stay in VGPRs)
#define LOADB(DST, TN)                                                         \
  do {                                                                         \
    const int dh_ = (TN) / 3 - 1, dw_ = (TN) % 3 - 1;                          \
    const int hb_ = wn + dh_ + 1;                                              \
    _Pragma("unroll") for (int j_ = 0; j_ < 4; ++j_) {                         \
      int r_ = hb_ * 66 + j_ * 16 + lrow + dw_ + 1;                            \
      DST[j_] = *(const bf16x8*)&Bsm[r_ * 32 + ((lk ^ ((r_ >> 1) & 3)) * 8)];  \
    }                                                                          \
  } while (0)

// MFMA cluster for one tap: uses USE[4], prefetches tap T+1's B-frags into PRE[4]
// in the MFMA shadow (T is compile-time after unroll).
#define TAP_MFMA(USE, PRE, T)                                                  \
  do {                                                                         \
    __builtin_amdgcn_s_setprio(1);                                             \
    _Pragma("unroll") for (int j_ = 0; j_ < 4; ++j_)                           \
      acc[0][j_] = __builtin_amdgcn_mfma_f32_16x16x32_bf16(af[0], USE[j_],     \
                                                           acc[0][j_], 0, 0, 0); \
    if ((T) < 8) { LOADB(PRE, (T) + 1); }                                      \
    _Pragma("unroll") for (int i_ = 1; i_ < 4; ++i_)                           \
      _Pragma("unroll") for (int j_ = 0; j_ < 4; ++j_)                         \
        acc[i_][j_] = __builtin_amdgcn_mfma_f32_16x16x32_bf16(af[i_], USE[j_], \
                                                              acc[i_][j_], 0, 0, 0); \
    __builtin_amdgcn_s_setprio(0);                                             \
  } while (0)

// ---------------- kernel 4: the conv (implicit GEMM, bf16 MFMA) ----------------
// grid: 2048 = 16 b * 4 mblk * 32 nblk; block 256 (4 waves, 2x2 over 128x128 tile)
// EXACT r3 skeleton (3 A-buffers, issueA 2-ahead, vmcnt(2) only, 1 raw
// barrier/phase, stageB inline at t==0 with publish barrier) + ONE change:
// B-frag cross-tap prefetch via named register arrays (bcur/bnxt, parity on
// compile-time t). Post-barrier critical path = 4 A-frag ds_reads only.
__global__ __launch_bounds__(256, 3) void k_conv(
    const float* __restrict__ x, const unsigned short* __restrict__ wpack,
    const float* __restrict__ s, const float* __restrict__ fscale,
    float* __restrict__ out) {
  __shared__ __align__(128) unsigned short Asm[3][128 * 32];  // [buf][oc_local][ic] swizzled
  __shared__ __align__(128) unsigned short Bsm[264 * 32];     // [h''*66 + w''][ic] swizzled

  const int bx = blockIdx.x;
  const int b = bx >> 7;
  const int mblk = (bx >> 5) & 3;
  const int nblk = bx & 31;

  const int tid = threadIdx.x;
  const int wave = tid >> 6, lane = tid & 63;
  const int wm = wave >> 1, wn = wave & 1;
  const int lrow = lane & 15, lk = lane >> 4;

  const int h0 = nblk * 2;  // this block's 2 output rows; halo rows h0-1..h0+2
  const float* xb = x + (size_t)b * IC * HW;
  const float* sb = s + b * IC;

  f32x4 acc[4][4];
#pragma unroll
  for (int i = 0; i < 4; ++i)
#pragma unroll
    for (int j = 0; j < 4; ++j) acc[i][j] = f32x4{0.f, 0.f, 0.f, 0.f};

  // zero the w-halo rows (w''==0 and w''==65 for the 4 h rows), once
  {
    int q = tid >> 5;  // 0..7
    int hh = q >> 1, wz = (q & 1) ? 65 : 0;
    Bsm[(hh * 66 + wz) * 32 + (tid & 31)] = 0;
  }

  // stage input tile for one 32-ic block: [4 h rows][64 w][32 ic], scaled by s
  auto stageB = [&](int icb) {
    const int hh = wave;     // 0..3
    const int w = lane;      // 0..63
    const int h_abs = h0 - 1 + hh;
    const bool vh = (h_abs >= 0) && (h_abs < HH);
    const int h_safe = vh ? h_abs : 0;
    const int r = hh * 66 + w + 1;
    const int swz = (r >> 1) & 3;
    const float* src = xb + (size_t)(icb * 32) * HW + h_safe * WW + w;
#pragma unroll
    for (int c = 0; c < 4; ++c) {
      unsigned int pk[4];
#pragma unroll
      for (int jj = 0; jj < 4; ++jj) {
        int ic = c * 8 + jj * 2;
        float m0 = vh ? sb[icb * 32 + ic] : 0.f;
        float m1 = vh ? sb[icb * 32 + ic + 1] : 0.f;
        float v0 = src[(size_t)ic * HW] * m0;
        float v1 = src[(size_t)(ic + 1) * HW] * m1;
        pk[jj] = (unsigned int)f2bf(v0) | ((unsigned int)f2bf(v1) << 16);
      }
      int cd = c ^ swz;
      *(uint4*)&Bsm[r * 32 + cd * 8] = make_uint4(pk[0], pk[1], pk[2], pk[3]);
    }
  };

  // async-stage one 128x32 weight tile (2 global_load_lds per wave per call)
  auto issueA = [&](int tap, int icb, int nb) {
    const unsigned short* base =
        wpack + ((size_t)(tap * OC + mblk * 128)) * IC + icb * 32;
#pragma unroll
    for (int q = 0; q < 2; ++q) {
      int r = wave * 32 + q * 16 + (lane >> 2);
      int cs = (lane & 3) ^ ((r >> 1) & 3);
      const unsigned short* g = base + (size_t)r * IC + cs * 8;
      unsigned short* l = &Asm[nb][(wave * 32 + q * 16) * 32];
      __builtin_amdgcn_global_load_lds(
          (const __attribute__((address_space(1))) void*)g,
          (__attribute__((address_space(3))) void*)l, 16, 0, 0);
    }
  };

  stageB(0);
  issueA(0, 0, 0);   // D(0) -> buf0
  issueA(1, 0, 1);   // D(1) -> buf1
  __syncthreads();   // prologue only: full drain + publish

  bf16x8 bcur[4], bnxt[4];  // two named B-frag sets; parity on compile-time t

  for (int icb = 0; icb < 16; ++icb) {
#pragma unroll
    for (int t = 0; t < 9; ++t) {
      // ---- arrival wait for D(p): only the next group (2 instrs) may remain ----
      if (t == 8) {
        if (icb == 15) { VMWAIT(0); } else { VMWAIT(2); }
      } else {
        VMWAIT(2);
      }
      __builtin_amdgcn_s_barrier();          // the ONE barrier per phase
      __builtin_amdgcn_sched_barrier(0);

      if (t == 0) {
        if (icb > 0) {
          // restage B inside the phase; all Bsm reads of the previous icb
          // completed before the arrival barrier (t==8 prefetches nothing).
          stageB(icb);
          asm volatile("s_waitcnt lgkmcnt(0)" ::: "memory");
          __builtin_amdgcn_s_barrier();      // publish new Bsm to the block
          __builtin_amdgcn_sched_barrier(0);
        }
        LOADB(bcur, 0);                      // tap 0's B-frags (t==0 only)
      }

      // ---- issue D(p+2) into buf (t+2)%3; safe: barrier(p) proved all waves
      //      consumed that buffer at phase p-1 ----
      if (t <= 6) {
        issueA(t + 2, icb, (t + 2) % 3);
      } else if (icb < 15) {
        issueA(t - 7, icb + 1, t - 7);       // t==7 -> tap0/buf0, t==8 -> tap1/buf1
      }

      // ---- A-frags for tap t (the only post-barrier-critical ds_reads) ----
      bf16x8 af[4];
#pragma unroll
      for (int i = 0; i < 4; ++i) {
        int r = wm * 64 + i * 16 + lrow;
        af[i] = *(const bf16x8*)&Asm[t % 3][r * 32 + ((lk ^ ((r >> 1) & 3)) * 8)];
      }

      // ---- MFMA cluster; tap t+1's B-frags issue in its shadow ----
      if ((t & 1) == 0) {
        TAP_MFMA(bcur, bnxt, t);
      } else {
        TAP_MFMA(bnxt, bcur, t);
      }
      __builtin_amdgcn_sched_barrier(0);
      // no second barrier: next phase's arrival barrier bounds skew to <1 phase
    }
  }

  // epilogue: scale by conv_scale*demod[b][oc], coalesced 64B stores
  const float* fsb = fscale + b * OC;
#pragma unroll
  for (int i = 0; i < 4; ++i) {
#pragma unroll
    for (int rr = 0; rr < 4; ++rr) {
      const int oc = mblk * 128 + wm * 64 + i * 16 + lk * 4 + rr;
      const float sc = fsb[oc];
      float* orow = out + ((size_t)(b * OC + oc)) * HW + nblk * 128 + wn * 64 + lrow;
#pragma unroll
      for (int j = 0; j < 4; ++j) orow[j * 16] = acc[i][j][rr] * sc;
    }
  }
}

// ---------------- launch --------------------------------------------------------
extern "C" void kernel_launch(void* const* d_in, const int* in_sizes, int n_in,
                              void* d_out, int out_size, void* d_ws, size_t ws_size,
                              hipStream_t stream) {
  const float* input = (const float*)d_in[0];       // [16,512,64,64]
  const float* style = (const float*)d_in[1];       // [16,512]
  const float* weight = (const float*)d_in[2];      // [1,512,512,3,3]
  const float* mod_weight = (const float*)d_in[3];  // [512,512]
  const float* mod_bias = (const float*)d_in[4];    // [512]
  float* out = (float*)d_out;

  char* ws = (char*)d_ws;
  constexpr size_t WPACK_B = (size_t)9 * OC * IC * 2;   // 4,718,592
  constexpr size_t W2SUM_B = (size_t)OC * IC * 4;       // 1,048,576
  constexpr size_t S_B = (size_t)BB * IC * 4;           // 32,768
  unsigned short* wpack = (unsigned short*)ws;
  float* w2sum = (float*)(ws + WPACK_B);
  float* s = (float*)(ws + WPACK_B + W2SUM_B);
  float* fscale = (float*)(ws + WPACK_B + W2SUM_B + S_B);

  k_style<<<BB, 256, 0, stream>>>(style, mod_weight, mod_bias, s);
  k_pack<<<OC, 256, 0, stream>>>(weight, wpack, w2sum);
  k_demod<<<BB, 256, 0, stream>>>(s, w2sum, fscale);
  k_conv<<<2048, 256, 0, stream>>>(input, wpack, s, fscale, out);
}